// Round 1
// baseline (555.812 us; speedup 1.0000x reference)
//
#include <hip/hip_runtime.h>
#include <hip/hip_bf16.h>
#include <hip/hip_fp16.h>

// Problem constants (from reference)
#define NN 50000
#define NE 800000
#define ET (NE + NN)          // edges + self loops = 850000
#define FIN 256
#define HC 192                // H*C = 3*64
#define NHEAD 3
#define CDIM 64
#define MAXDEG 128            // fast-path cap; Poisson(17) max over 50K nodes ~45
#define MLW 384               // hml row width (mu 0..191 | lv 192..383)

typedef short short8 __attribute__((ext_vector_type(8)));
typedef float f32x4 __attribute__((ext_vector_type(4)));

// ---------------------------------------------------------------------------
// CSR build: histogram -> scan -> scatter (graph shared by all 3 GAT layers)
// ---------------------------------------------------------------------------
__global__ __launch_bounds__(256) void hist_kernel(const int* __restrict__ ei,
                                                   int* __restrict__ cnt) {
    int e = blockIdx.x * 256 + threadIdx.x;
    if (e >= ET) return;
    int dst = (e < NE) ? ei[NE + e] : (e - NE);
    atomicAdd(&cnt[dst], 1);
}

#define SCAN_BLK 1024
__global__ __launch_bounds__(SCAN_BLK) void scan1_kernel(const int* __restrict__ cnt,
                                                         int* __restrict__ row_ptr,
                                                         int* __restrict__ partials) {
    __shared__ int sm[SCAN_BLK];
    int t = threadIdx.x;
    int g = blockIdx.x * SCAN_BLK + t;
    int v = (g < NN) ? cnt[g] : 0;
    sm[t] = v;
    __syncthreads();
    for (int off = 1; off < SCAN_BLK; off <<= 1) {
        int u = (t >= off) ? sm[t - off] : 0;
        __syncthreads();
        sm[t] += u;
        __syncthreads();
    }
    if (g < NN) row_ptr[g + 1] = sm[t];
    if (t == SCAN_BLK - 1) partials[blockIdx.x] = sm[t];
}

__global__ __launch_bounds__(64) void scan2_kernel(int* __restrict__ partials, int nb) {
    int t = threadIdx.x;
    int v = (t < nb) ? partials[t] : 0;
    int x = v;
    for (int off = 1; off < 64; off <<= 1) {
        int y = __shfl_up(x, off);
        if (t >= off) x += y;
    }
    if (t < nb) partials[t] = x - v;
}

// also zeroes cnt so scatter can reuse it (saves a memset dispatch)
__global__ __launch_bounds__(SCAN_BLK) void scan3_kernel(int* __restrict__ row_ptr,
                                                         const int* __restrict__ partials,
                                                         int* __restrict__ cnt) {
    int g = blockIdx.x * SCAN_BLK + threadIdx.x;
    if (g < NN) {
        row_ptr[g + 1] += partials[blockIdx.x];
        cnt[g] = 0;
    }
    if (g == 0) row_ptr[0] = 0;
}

__global__ __launch_bounds__(256) void scatter_kernel(const int* __restrict__ ei,
                                                      int* __restrict__ cnt,
                                                      const int* __restrict__ row_ptr,
                                                      int* __restrict__ csr_src) {
    int e = blockIdx.x * 256 + threadIdx.x;
    if (e >= ET) return;
    int src, dst;
    if (e < NE) { src = ei[e]; dst = ei[NE + e]; }
    else        { src = e - NE; dst = e - NE; }
    int pos = atomicAdd(&cnt[dst], 1);
    csr_src[row_ptr[dst] + pos] = src;
}

// ---------------------------------------------------------------------------
// fp32 -> bf16 split helpers
// ---------------------------------------------------------------------------
__device__ __forceinline__ unsigned short f2bf(float f) {
    unsigned int u = __float_as_uint(f);
    unsigned int r = (u + 0x7FFFu + ((u >> 16) & 1u)) >> 16;   // RNE
    return (unsigned short)r;
}
__device__ __forceinline__ float bf2f(unsigned short h) {
    return __uint_as_float(((unsigned int)h) << 16);
}

// ---------------------------------------------------------------------------
// Pre-split: fp32 array -> (bf16 hi, bf16 lo) planes, vectorized x4.
// Hoists the per-tile conversion VALU out of the GEMMs (was redone 3x/6x).
// Bit-identical to the in-GEMM split (same RNE computation).
// ---------------------------------------------------------------------------
__global__ __launch_bounds__(256) void split_kernel(const float* __restrict__ in,
                                                    unsigned short* __restrict__ hi,
                                                    unsigned short* __restrict__ lo,
                                                    int n4) {
    int i = blockIdx.x * 256 + threadIdx.x;
    int stride = gridDim.x * 256;
    for (; i < n4; i += stride) {
        float4 v = reinterpret_cast<const float4*>(in)[i];
        unsigned short h0 = f2bf(v.x), h1 = f2bf(v.y), h2 = f2bf(v.z), h3 = f2bf(v.w);
        unsigned short g0 = f2bf(v.x - bf2f(h0)), g1 = f2bf(v.y - bf2f(h1));
        unsigned short g2 = f2bf(v.z - bf2f(h2)), g3 = f2bf(v.w - bf2f(h3));
        reinterpret_cast<uint2*>(hi)[i] =
            make_uint2((unsigned)h0 | ((unsigned)h1 << 16), (unsigned)h2 | ((unsigned)h3 << 16));
        reinterpret_cast<uint2*>(lo)[i] =
            make_uint2((unsigned)g0 | ((unsigned)g1 << 16), (unsigned)g2 | ((unsigned)g3 << 16));
    }
}

// ---------------------------------------------------------------------------
// Split-bf16 MFMA GEMM on PRE-SPLIT operands:
// C[M,N] = A[M,K] * B[N,K]^T with A,B given as bf16 hi/lo planes.
// BM=128, BN=64, BK=32; 256 threads = 4 waves (2x2), wave tile 64x32.
// Staging is now pure 16B loads + 16B LDS writes (no conversion VALU).
// ---------------------------------------------------------------------------
#define LSTR 40
__device__ __forceinline__ void gemm_pre_core(const unsigned short* __restrict__ Agh,
                                              const unsigned short* __restrict__ Agl,
                                              const unsigned short* __restrict__ Bgh,
                                              const unsigned short* __restrict__ Bgl,
                                              __half* __restrict__ C,
                                              int M, int CS, int K) {
    __shared__ unsigned short Ah[128 * LSTR], Al[128 * LSTR];
    __shared__ unsigned short Bh[64 * LSTR],  Bl[64 * LSTR];

    const int tid  = threadIdx.x;
    const int lane = tid & 63;
    const int wid  = tid >> 6;
    const int wm   = wid & 1;
    const int wn   = wid >> 1;
    const int quad = lane >> 4;
    const int l15  = lane & 15;
    const int m0   = blockIdx.x * 128;
    const int n0   = blockIdx.y * 64;

    f32x4 acc[4][2];
#pragma unroll
    for (int i = 0; i < 4; i++)
#pragma unroll
        for (int j = 0; j < 2; j++) acc[i][j] = (f32x4)(0.f);

    // A tile: 128 rows x 32 cols bf16 = 512 chunks of 8 elems (16B); 2 per thread.
    // B tile: 64 rows  x 32 cols      = 256 chunks; 1 per thread.
    const int ca_r0   = (tid) >> 2;            // chunk row for p=0 (0..63)
    const int ca_r1   = (tid + 256) >> 2;      // chunk row for p=1 (64..127)
    const int ca_col  = (tid & 3) * 8;         // elem offset 0/8/16/24
    const int cb_r    = tid >> 2;
    const int cb_col  = (tid & 3) * 8;

    for (int k0 = 0; k0 < K; k0 += 32) {
        {
            int gm0 = m0 + ca_r0;
            int gm1 = m0 + ca_r1;
            short8 vh0 = (short8)0, vl0 = (short8)0, vh1 = (short8)0, vl1 = (short8)0;
            if (gm0 < M) {
                size_t g = (size_t)gm0 * K + k0 + ca_col;
                vh0 = *reinterpret_cast<const short8*>(&Agh[g]);
                vl0 = *reinterpret_cast<const short8*>(&Agl[g]);
            }
            if (gm1 < M) {
                size_t g = (size_t)gm1 * K + k0 + ca_col;
                vh1 = *reinterpret_cast<const short8*>(&Agh[g]);
                vl1 = *reinterpret_cast<const short8*>(&Agl[g]);
            }
            // B chunk
            size_t gb = (size_t)(n0 + cb_r) * K + k0 + cb_col;
            short8 bh = *reinterpret_cast<const short8*>(&Bgh[gb]);
            short8 bl = *reinterpret_cast<const short8*>(&Bgl[gb]);

            int offA0 = ca_r0 * LSTR + ca_col;
            int offA1 = ca_r1 * LSTR + ca_col;
            int offB  = cb_r * LSTR + cb_col;
            *reinterpret_cast<short8*>(&Ah[offA0]) = vh0;
            *reinterpret_cast<short8*>(&Al[offA0]) = vl0;
            *reinterpret_cast<short8*>(&Ah[offA1]) = vh1;
            *reinterpret_cast<short8*>(&Al[offA1]) = vl1;
            *reinterpret_cast<short8*>(&Bh[offB])  = bh;
            *reinterpret_cast<short8*>(&Bl[offB])  = bl;
        }
        __syncthreads();

        short8 afh[4], afl[4], bfh[2], bfl[2];
#pragma unroll
        for (int tm = 0; tm < 4; tm++) {
            int off = (wm * 64 + tm * 16 + l15) * LSTR + quad * 8;
            afh[tm] = *reinterpret_cast<const short8*>(&Ah[off]);
            afl[tm] = *reinterpret_cast<const short8*>(&Al[off]);
        }
#pragma unroll
        for (int tn = 0; tn < 2; tn++) {
            int off = (wn * 32 + tn * 16 + l15) * LSTR + quad * 8;
            bfh[tn] = *reinterpret_cast<const short8*>(&Bh[off]);
            bfl[tn] = *reinterpret_cast<const short8*>(&Bl[off]);
        }
#pragma unroll
        for (int tm = 0; tm < 4; tm++)
#pragma unroll
            for (int tn = 0; tn < 2; tn++) {
                acc[tm][tn] = __builtin_amdgcn_mfma_f32_16x16x32_bf16(afh[tm], bfh[tn], acc[tm][tn], 0, 0, 0);
                acc[tm][tn] = __builtin_amdgcn_mfma_f32_16x16x32_bf16(afh[tm], bfl[tn], acc[tm][tn], 0, 0, 0);
                acc[tm][tn] = __builtin_amdgcn_mfma_f32_16x16x32_bf16(afl[tm], bfh[tn], acc[tm][tn], 0, 0, 0);
            }
        __syncthreads();
    }

#pragma unroll
    for (int tm = 0; tm < 4; tm++) {
        int rbase = m0 + wm * 64 + tm * 16 + quad * 4;
#pragma unroll
        for (int r = 0; r < 4; r++) {
            int row = rbase + r;
            if (row < M) {
#pragma unroll
                for (int tn = 0; tn < 2; tn++) {
                    int col = n0 + wn * 32 + tn * 16 + l15;
                    C[(size_t)row * CS + col] = __float2half(acc[tm][tn][r]);
                }
            }
        }
    }
}

__global__ __launch_bounds__(256) void sgemm1(const unsigned short* __restrict__ Ah,
                                              const unsigned short* __restrict__ Al,
                                              const unsigned short* __restrict__ Bh,
                                              const unsigned short* __restrict__ Bl,
                                              __half* __restrict__ C) {
    gemm_pre_core(Ah, Al, Bh, Bl, C, NN, HC, FIN);       // N=192
}

__global__ __launch_bounds__(256) void sgemm23(const unsigned short* __restrict__ Ah,
                                               const unsigned short* __restrict__ Al,
                                               const unsigned short* __restrict__ Bh,
                                               const unsigned short* __restrict__ Bl,
                                               __half* __restrict__ C) {
    gemm_pre_core(Ah, Al, Bh, Bl, C, NN, MLW, HC);       // N=384 = mu|lv fused
}

// ---------------------------------------------------------------------------
// Attention logits, layer 1 (h stride HC)
// ---------------------------------------------------------------------------
__global__ __launch_bounds__(256) void al_h_kernel(const __half* __restrict__ h,
                                                   const float* __restrict__ a_src,
                                                   const float* __restrict__ a_dst,
                                                   float* __restrict__ al_src,
                                                   float* __restrict__ al_dst) {
    int wid = (blockIdx.x * 256 + threadIdx.x) >> 6;
    int lane = threadIdx.x & 63;
    if (wid >= NN * NHEAD) return;
    int n = wid / 3;
    int head = wid - n * 3;
    float v = __half2float(h[(size_t)n * HC + head * CDIM + lane]);
    float ps = v * a_src[head * CDIM + lane];
    float pd = v * a_dst[head * CDIM + lane];
#pragma unroll
    for (int off = 32; off; off >>= 1) {
        ps += __shfl_xor(ps, off);
        pd += __shfl_xor(pd, off);
    }
    if (lane == 0) { al_src[wid] = ps; al_dst[wid] = pd; }
}

// Fused mu+lv logits from hml (stride MLW): 4 outputs in one pass.
__global__ __launch_bounds__(256) void al_ml_kernel(const __half* __restrict__ hml,
                                                    const float* __restrict__ amus,
                                                    const float* __restrict__ amud,
                                                    const float* __restrict__ alvs,
                                                    const float* __restrict__ alvd,
                                                    float* __restrict__ alms,
                                                    float* __restrict__ almd,
                                                    float* __restrict__ alls,
                                                    float* __restrict__ alld) {
    int wid = (blockIdx.x * 256 + threadIdx.x) >> 6;
    int lane = threadIdx.x & 63;
    if (wid >= NN * NHEAD) return;
    int n = wid / 3;
    int head = wid - n * 3;
    int c = head * CDIM + lane;
    float vm = __half2float(hml[(size_t)n * MLW + c]);
    float vl = __half2float(hml[(size_t)n * MLW + 192 + c]);
    float ms = vm * amus[c], md = vm * amud[c];
    float ls = vl * alvs[c], ld = vl * alvd[c];
#pragma unroll
    for (int off = 32; off; off >>= 1) {
        ms += __shfl_xor(ms, off);
        md += __shfl_xor(md, off);
        ls += __shfl_xor(ls, off);
        ld += __shfl_xor(ld, off);
    }
    if (lane == 0) { alms[wid] = ms; almd[wid] = md; alls[wid] = ls; alld[wid] = ld; }
}

// ---------------------------------------------------------------------------
// Per-wave softmax weights into LDS; returns softmax denominator.
// ---------------------------------------------------------------------------
__device__ __forceinline__ float edge_weights(const int* slds3, float* wrow,
                                              const float* __restrict__ al_s,
                                              float ad, int head, int deg, int lane) {
    float m = -1e30f;
    for (int j = lane; j < deg; j += 64) {
        float a = al_s[slds3[j] + head] + ad;
        a = a > 0.f ? a : 0.2f * a;
        wrow[j] = a;
        m = fmaxf(m, a);
    }
#pragma unroll
    for (int off = 32; off; off >>= 1) m = fmaxf(m, __shfl_xor(m, off));
    float ssum = 0.f;
    for (int j = lane; j < deg; j += 64) {
        float w = __expf(wrow[j] - m);
        wrow[j] = w;
        ssum += w;
    }
#pragma unroll
    for (int off = 32; off; off >>= 1) ssum += __shfl_xor(ssum, off);
    return ssum;
}

__device__ __forceinline__ float4 fma4h(float w, uint2 u, float4 acc) {
    __half2 p0 = *reinterpret_cast<__half2*>(&u.x);
    __half2 p1 = *reinterpret_cast<__half2*>(&u.y);
    float2 f0 = __half22float2(p0);
    float2 f1 = __half22float2(p1);
    acc.x = fmaf(w, f0.x, acc.x); acc.y = fmaf(w, f0.y, acc.y);
    acc.z = fmaf(w, f1.x, acc.z); acc.w = fmaf(w, f1.y, acc.w);
    return acc;
}

// ---------------------------------------------------------------------------
// Layer-1 aggregation (concat + bias + relu). 3 waves/node, fp16 h.
// Output written as PRE-SPLIT bf16 hi/lo planes (bit-identical to the split
// sgemm23 would do internally on the fp32 value).
// ---------------------------------------------------------------------------
__global__ __launch_bounds__(192) void agg_cat_kernel(const int* __restrict__ row_ptr,
                                                      const int* __restrict__ csr_src,
                                                      const __half* __restrict__ h,
                                                      const float* __restrict__ al_src,
                                                      const float* __restrict__ al_dst,
                                                      const float* __restrict__ bias,
                                                      unsigned short* __restrict__ outh,
                                                      unsigned short* __restrict__ outl) {
    __shared__ int slds3[MAXDEG];
    __shared__ int sldsHC[MAXDEG];
    __shared__ float wlds[3][MAXDEG];
    int n = blockIdx.x;
    int head = threadIdx.x >> 6;
    int lane = threadIdx.x & 63;
    int start = row_ptr[n];
    int deg = row_ptr[n + 1] - start;
    float ad = al_dst[n * 3 + head];

    if (deg <= MAXDEG) {
        if (threadIdx.x < deg) {
            int s = csr_src[start + threadIdx.x];
            slds3[threadIdx.x] = s * 3;
            sldsHC[threadIdx.x] = s * HC;
        }
        __syncthreads();
        float ssum = edge_weights(slds3, wlds[head], al_src, ad, head, deg, lane);
        const int sub = lane >> 4, l16 = lane & 15;
        const int hoff = head * CDIM + l16 * 4;
        const float* wrow = wlds[head];
        float4 acc = make_float4(0.f, 0.f, 0.f, 0.f);
        int j = 0;
        for (; j + 16 <= deg; j += 16) {
            int s0 = sldsHC[j + sub],      s1 = sldsHC[j + 4 + sub];
            int s2 = sldsHC[j + 8 + sub],  s3 = sldsHC[j + 12 + sub];
            float w0 = wrow[j + sub],      w1 = wrow[j + 4 + sub];
            float w2 = wrow[j + 8 + sub],  w3 = wrow[j + 12 + sub];
            uint2 u0 = *reinterpret_cast<const uint2*>(&h[s0 + hoff]);
            uint2 u1 = *reinterpret_cast<const uint2*>(&h[s1 + hoff]);
            uint2 u2 = *reinterpret_cast<const uint2*>(&h[s2 + hoff]);
            uint2 u3 = *reinterpret_cast<const uint2*>(&h[s3 + hoff]);
            acc = fma4h(w0, u0, acc); acc = fma4h(w1, u1, acc);
            acc = fma4h(w2, u2, acc); acc = fma4h(w3, u3, acc);
        }
        for (; j + 4 <= deg; j += 4) {
            int s = sldsHC[j + sub];
            float w = wrow[j + sub];
            uint2 u = *reinterpret_cast<const uint2*>(&h[s + hoff]);
            acc = fma4h(w, u, acc);
        }
        if (sub < deg - j) {
            int s = sldsHC[j + sub];
            float w = wrow[j + sub];
            uint2 u = *reinterpret_cast<const uint2*>(&h[s + hoff]);
            acc = fma4h(w, u, acc);
        }
#pragma unroll
        for (int off = 16; off <= 32; off <<= 1) {
            acc.x += __shfl_xor(acc.x, off);
            acc.y += __shfl_xor(acc.y, off);
            acc.z += __shfl_xor(acc.z, off);
            acc.w += __shfl_xor(acc.w, off);
        }
        if (lane < 16) {
            float inv = 1.f / (ssum + 1e-16f);
            const float4 b4 = *reinterpret_cast<const float4*>(&bias[head * CDIM + l16 * 4]);
            float4 o;
            o.x = fmaxf(fmaf(acc.x, inv, b4.x), 0.f);
            o.y = fmaxf(fmaf(acc.y, inv, b4.y), 0.f);
            o.z = fmaxf(fmaf(acc.z, inv, b4.z), 0.f);
            o.w = fmaxf(fmaf(acc.w, inv, b4.w), 0.f);
            unsigned short h0 = f2bf(o.x), h1 = f2bf(o.y), h2 = f2bf(o.z), h3 = f2bf(o.w);
            unsigned short g0 = f2bf(o.x - bf2f(h0)), g1 = f2bf(o.y - bf2f(h1));
            unsigned short g2 = f2bf(o.z - bf2f(h2)), g3 = f2bf(o.w - bf2f(h3));
            size_t idx = (size_t)n * HC + head * CDIM + l16 * 4;
            *reinterpret_cast<uint2*>(&outh[idx]) =
                make_uint2((unsigned)h0 | ((unsigned)h1 << 16), (unsigned)h2 | ((unsigned)h3 << 16));
            *reinterpret_cast<uint2*>(&outl[idx]) =
                make_uint2((unsigned)g0 | ((unsigned)g1 << 16), (unsigned)g2 | ((unsigned)g3 << 16));
        }
    } else {  // streaming fallback (not hit for this graph; correctness-safe)
        float m = -1e30f;
        for (int j = start + lane; j < start + deg; j += 64) {
            float a = al_src[csr_src[j] * 3 + head] + ad;
            a = a > 0.f ? a : 0.2f * a;
            m = fmaxf(m, a);
        }
#pragma unroll
        for (int off = 32; off; off >>= 1) m = fmaxf(m, __shfl_xor(m, off));
        float acc = 0.f, ssum = 0.f;
        for (int j = start; j < start + deg; ++j) {
            int s = csr_src[j];
            float a = al_src[s * 3 + head] + ad;
            a = a > 0.f ? a : 0.2f * a;
            float w = __expf(a - m);
            ssum += w;
            acc = fmaf(w, __half2float(h[(size_t)s * HC + head * CDIM + lane]), acc);
        }
        float o = acc / (ssum + 1e-16f) + bias[head * CDIM + lane];
        o = fmaxf(o, 0.f);
        unsigned short hh = f2bf(o);
        unsigned short gg = f2bf(o - bf2f(hh));
        size_t idx = (size_t)n * HC + head * CDIM + lane;
        outh[idx] = hh;
        outl[idx] = gg;
    }
}

// ---------------------------------------------------------------------------
// mu/lv aggregation fused over interleaved hml[n][384]: 3 waves/node, each
// wave = one head, both mu & lv; 16 edges/iter -> 8 loads in flight.
// ---------------------------------------------------------------------------
__global__ __launch_bounds__(192) void agg_mean2_kernel(const int* __restrict__ row_ptr,
                                                        const int* __restrict__ csr_src,
                                                        const __half* __restrict__ hml,
                                                        const float* __restrict__ alms,
                                                        const float* __restrict__ almd,
                                                        const float* __restrict__ alls,
                                                        const float* __restrict__ alld,
                                                        const float* __restrict__ b_mu,
                                                        const float* __restrict__ b_lv,
                                                        float* __restrict__ out) {
    __shared__ int slds3[MAXDEG];
    __shared__ int sldsML[MAXDEG];
    __shared__ float wm_[3][MAXDEG], wl_[3][MAXDEG];
    __shared__ __align__(16) float red[6][64];
    int n = blockIdx.x;
    int head = threadIdx.x >> 6;   // 0..2
    int lane = threadIdx.x & 63;
    int start = row_ptr[n];
    int deg = row_ptr[n + 1] - start;
    float adm = almd[n * 3 + head];
    float adl = alld[n * 3 + head];

    if (deg <= MAXDEG) {
        if (threadIdx.x < deg) {
            int s = csr_src[start + threadIdx.x];
            slds3[threadIdx.x] = s * 3;
            sldsML[threadIdx.x] = s * MLW;
        }
        __syncthreads();
        // softmax weights for mu and lv, interleaved
        float mm = -1e30f, ml = -1e30f;
        for (int j = lane; j < deg; j += 64) {
            int idx = slds3[j] + head;
            float am = alms[idx] + adm;
            float av = alls[idx] + adl;
            am = am > 0.f ? am : 0.2f * am;
            av = av > 0.f ? av : 0.2f * av;
            wm_[head][j] = am; wl_[head][j] = av;
            mm = fmaxf(mm, am); ml = fmaxf(ml, av);
        }
#pragma unroll
        for (int off = 32; off; off >>= 1) {
            mm = fmaxf(mm, __shfl_xor(mm, off));
            ml = fmaxf(ml, __shfl_xor(ml, off));
        }
        float sm = 0.f, sl = 0.f;
        for (int j = lane; j < deg; j += 64) {
            float em = __expf(wm_[head][j] - mm); wm_[head][j] = em; sm += em;
            float el = __expf(wl_[head][j] - ml); wl_[head][j] = el; sl += el;
        }
#pragma unroll
        for (int off = 32; off; off >>= 1) {
            sm += __shfl_xor(sm, off);
            sl += __shfl_xor(sl, off);
        }
        // joint gather: 8 loads in flight per iteration
        const int sub = lane >> 4, l16 = lane & 15;
        const int hoffm = head * CDIM + l16 * 4;
        const int hoffl = hoffm + 192;
        float4 am4 = make_float4(0.f, 0.f, 0.f, 0.f);
        float4 al4 = make_float4(0.f, 0.f, 0.f, 0.f);
        int j = 0;
        for (; j + 16 <= deg; j += 16) {
            int s0 = sldsML[j + sub],     s1 = sldsML[j + 4 + sub];
            int s2 = sldsML[j + 8 + sub], s3 = sldsML[j + 12 + sub];
            float wm0 = wm_[head][j + sub],      wm1 = wm_[head][j + 4 + sub];
            float wm2 = wm_[head][j + 8 + sub],  wm3 = wm_[head][j + 12 + sub];
            float wl0 = wl_[head][j + sub],      wl1 = wl_[head][j + 4 + sub];
            float wl2 = wl_[head][j + 8 + sub],  wl3 = wl_[head][j + 12 + sub];
            uint2 uM0 = *reinterpret_cast<const uint2*>(&hml[s0 + hoffm]);
            uint2 uL0 = *reinterpret_cast<const uint2*>(&hml[s0 + hoffl]);
            uint2 uM1 = *reinterpret_cast<const uint2*>(&hml[s1 + hoffm]);
            uint2 uL1 = *reinterpret_cast<const uint2*>(&hml[s1 + hoffl]);
            uint2 uM2 = *reinterpret_cast<const uint2*>(&hml[s2 + hoffm]);
            uint2 uL2 = *reinterpret_cast<const uint2*>(&hml[s2 + hoffl]);
            uint2 uM3 = *reinterpret_cast<const uint2*>(&hml[s3 + hoffm]);
            uint2 uL3 = *reinterpret_cast<const uint2*>(&hml[s3 + hoffl]);
            am4 = fma4h(wm0, uM0, am4); al4 = fma4h(wl0, uL0, al4);
            am4 = fma4h(wm1, uM1, am4); al4 = fma4h(wl1, uL1, al4);
            am4 = fma4h(wm2, uM2, am4); al4 = fma4h(wl2, uL2, al4);
            am4 = fma4h(wm3, uM3, am4); al4 = fma4h(wl3, uL3, al4);
        }
        for (; j + 4 <= deg; j += 4) {
            int s = sldsML[j + sub];
            float wmA = wm_[head][j + sub], wlA = wl_[head][j + sub];
            uint2 uM = *reinterpret_cast<const uint2*>(&hml[s + hoffm]);
            uint2 uL = *reinterpret_cast<const uint2*>(&hml[s + hoffl]);
            am4 = fma4h(wmA, uM, am4); al4 = fma4h(wlA, uL, al4);
        }
        if (sub < deg - j) {
            int s = sldsML[j + sub];
            float wmA = wm_[head][j + sub], wlA = wl_[head][j + sub];
            uint2 uM = *reinterpret_cast<const uint2*>(&hml[s + hoffm]);
            uint2 uL = *reinterpret_cast<const uint2*>(&hml[s + hoffl]);
            am4 = fma4h(wmA, uM, am4); al4 = fma4h(wlA, uL, al4);
        }
#pragma unroll
        for (int off = 16; off <= 32; off <<= 1) {
            am4.x += __shfl_xor(am4.x, off); am4.y += __shfl_xor(am4.y, off);
            am4.z += __shfl_xor(am4.z, off); am4.w += __shfl_xor(am4.w, off);
            al4.x += __shfl_xor(al4.x, off); al4.y += __shfl_xor(al4.y, off);
            al4.z += __shfl_xor(al4.z, off); al4.w += __shfl_xor(al4.w, off);
        }
        if (lane < 16) {
            float invm = 1.f / (sm + 1e-16f);
            float invl = 1.f / (sl + 1e-16f);
            float4 rm, rl;
            rm.x = am4.x * invm; rm.y = am4.y * invm; rm.z = am4.z * invm; rm.w = am4.w * invm;
            rl.x = al4.x * invl; rl.y = al4.y * invl; rl.z = al4.z * invl; rl.w = al4.w * invl;
            *reinterpret_cast<float4*>(&red[head][l16 * 4]) = rm;
            *reinterpret_cast<float4*>(&red[3 + head][l16 * 4]) = rl;
        }
    } else {  // streaming fallback (not hit; correctness-safe)
        for (int pass = 0; pass < 2; ++pass) {
            const float* as = pass ? alls : alms;
            float ad = pass ? adl : adm;
            int coff = pass ? 192 : 0;
            float m = -1e30f;
            for (int j = start + lane; j < start + deg; j += 64) {
                float a = as[csr_src[j] * 3 + head] + ad;
                a = a > 0.f ? a : 0.2f * a;
                m = fmaxf(m, a);
            }
#pragma unroll
            for (int off = 32; off; off >>= 1) m = fmaxf(m, __shfl_xor(m, off));
            float acc = 0.f, ssum = 0.f;
            for (int j = start; j < start + deg; ++j) {
                int s = csr_src[j];
                float a = as[s * 3 + head] + ad;
                a = a > 0.f ? a : 0.2f * a;
                float w = __expf(a - m);
                ssum += w;
                acc = fmaf(w, __half2float(hml[(size_t)s * MLW + coff + head * CDIM + lane]), acc);
            }
            red[pass * 3 + head][lane] = acc / (ssum + 1e-16f);
        }
    }
    __syncthreads();
    if (threadIdx.x < 64) {
        out[(size_t)n * CDIM + lane] =
            (red[0][lane] + red[1][lane] + red[2][lane]) * (1.f / 3.f) + b_mu[lane];
    } else if (threadIdx.x < 128) {
        out[(size_t)NN * CDIM + (size_t)n * CDIM + lane] =
            (red[3][lane] + red[4][lane] + red[5][lane]) * (1.f / 3.f) + b_lv[lane];
    }
}

// ---------------------------------------------------------------------------
extern "C" void kernel_launch(void* const* d_in, const int* in_sizes, int n_in,
                              void* d_out, int out_size, void* d_ws, size_t ws_size,
                              hipStream_t stream) {
    const float* x    = (const float*)d_in[0];
    const int*   ei   = (const int*)d_in[1];
    const float* W1   = (const float*)d_in[2];
    const float* a1s  = (const float*)d_in[3];
    const float* a1d  = (const float*)d_in[4];
    const float* b1   = (const float*)d_in[5];
    const float* Wmu  = (const float*)d_in[6];
    const float* amus = (const float*)d_in[7];
    const float* amud = (const float*)d_in[8];
    const float* bmu  = (const float*)d_in[9];
    const float* Wlv  = (const float*)d_in[10];
    const float* alvs = (const float*)d_in[11];
    const float* alvd = (const float*)d_in[12];
    const float* blv  = (const float*)d_in[13];
    float* out = (float*)d_out;

    // workspace carve (256B aligned)
    size_t off = 0;
    auto carve = [&](size_t bytes) {
        void* p = (char*)d_ws + off;
        off += (bytes + 255) & ~(size_t)255;
        return p;
    };
    int*    cnt      = (int*)carve((size_t)NN * 4);
    int*    row_ptr  = (int*)carve((size_t)(NN + 1) * 4);
    int*    partials = (int*)carve(64 * 4);
    int*    csr      = (int*)carve((size_t)ET * 4);
    __half* h1f16    = (__half*)carve((size_t)NN * HC * 2);
    __half* hml      = (__half*)carve((size_t)NN * MLW * 2);
    unsigned short* xh  = (unsigned short*)carve((size_t)NN * FIN * 2);
    unsigned short* xl  = (unsigned short*)carve((size_t)NN * FIN * 2);
    unsigned short* hh  = (unsigned short*)carve((size_t)NN * HC * 2);
    unsigned short* hl  = (unsigned short*)carve((size_t)NN * HC * 2);
    unsigned short* w1h = (unsigned short*)carve((size_t)HC * FIN * 2);
    unsigned short* w1l = (unsigned short*)carve((size_t)HC * FIN * 2);
    unsigned short* wmlh = (unsigned short*)carve((size_t)MLW * HC * 2);
    unsigned short* wmll = (unsigned short*)carve((size_t)MLW * HC * 2);
    float*  al1s     = (float*)carve((size_t)NN * 3 * 4);
    float*  al1d     = (float*)carve((size_t)NN * 3 * 4);
    float*  alms     = (float*)carve((size_t)NN * 3 * 4);
    float*  almd     = (float*)carve((size_t)NN * 3 * 4);
    float*  alls     = (float*)carve((size_t)NN * 3 * 4);
    float*  alld     = (float*)carve((size_t)NN * 3 * 4);

    const int scan_blocks = (NN + SCAN_BLK - 1) / SCAN_BLK;  // 49

    // ---- CSR build (shared by all 3 layers) ----
    hipMemsetAsync(cnt, 0, (size_t)NN * 4, stream);
    hist_kernel<<<(ET + 255) / 256, 256, 0, stream>>>(ei, cnt);
    scan1_kernel<<<scan_blocks, SCAN_BLK, 0, stream>>>(cnt, row_ptr, partials);
    scan2_kernel<<<1, 64, 0, stream>>>(partials, scan_blocks);
    scan3_kernel<<<scan_blocks, SCAN_BLK, 0, stream>>>(row_ptr, partials, cnt);
    scatter_kernel<<<(ET + 255) / 256, 256, 0, stream>>>(ei, cnt, row_ptr, csr);

    // ---- Pre-split operands (hoisted conversion; bit-identical numerics) ----
    split_kernel<<<2048, 256, 0, stream>>>(x, xh, xl, NN * FIN / 4);
    split_kernel<<<48, 256, 0, stream>>>(W1, w1h, w1l, HC * FIN / 4);
    split_kernel<<<36, 256, 0, stream>>>(Wmu, wmlh, wmll, HC * HC / 4);
    split_kernel<<<36, 256, 0, stream>>>(Wlv, wmlh + (size_t)HC * HC,
                                         wmll + (size_t)HC * HC, HC * HC / 4);

    // ---- Layer 1 (fp16 h) ----
    dim3 g1((NN + 127) / 128, HC / 64);
    sgemm1<<<g1, 256, 0, stream>>>(xh, xl, w1h, w1l, h1f16);
    al_h_kernel<<<(NN * 3 + 3) / 4, 256, 0, stream>>>(h1f16, a1s, a1d, al1s, al1d);
    agg_cat_kernel<<<NN, 192, 0, stream>>>(row_ptr, csr, h1f16, al1s, al1d, b1, hh, hl);

    // ---- Layers mu / lv fused: one GEMM (N=384), one al pass ----
    dim3 g2((NN + 127) / 128, MLW / 64);
    sgemm23<<<g2, 256, 0, stream>>>(hh, hl, wmlh, wmll, hml);
    al_ml_kernel<<<(NN * 3 + 3) / 4, 256, 0, stream>>>(hml, amus, amud, alvs, alvd,
                                                       alms, almd, alls, alld);
    agg_mean2_kernel<<<NN, 192, 0, stream>>>(row_ptr, csr, hml,
                                             alms, almd, alls, alld, bmu, blv, out);
}

// Round 3
// 528.394 us; speedup vs baseline: 1.0519x; 1.0519x over previous
//
#include <hip/hip_runtime.h>
#include <hip/hip_bf16.h>
#include <hip/hip_fp16.h>

// Problem constants (from reference)
#define NN 50000
#define NE 800000
#define ET (NE + NN)          // edges + self loops = 850000
#define FIN 256
#define HC 192                // H*C = 3*64
#define NHEAD 3
#define CDIM 64
#define MAXDEG 128            // fast-path cap; Poisson(17) max over 50K nodes ~45
#define MLW 384               // hml row width (mu 0..191 | lv 192..383)

typedef short short8 __attribute__((ext_vector_type(8)));
typedef float f32x4 __attribute__((ext_vector_type(4)));

// ---------------------------------------------------------------------------
// CSR build: histogram -> scan -> scatter (graph shared by all 3 GAT layers)
// ---------------------------------------------------------------------------
__global__ __launch_bounds__(256) void hist_kernel(const int* __restrict__ ei,
                                                   int* __restrict__ cnt) {
    int e = blockIdx.x * 256 + threadIdx.x;
    if (e >= ET) return;
    int dst = (e < NE) ? ei[NE + e] : (e - NE);
    atomicAdd(&cnt[dst], 1);
}

#define SCAN_BLK 1024
__global__ __launch_bounds__(SCAN_BLK) void scan1_kernel(const int* __restrict__ cnt,
                                                         int* __restrict__ row_ptr,
                                                         int* __restrict__ partials) {
    __shared__ int sm[SCAN_BLK];
    int t = threadIdx.x;
    int g = blockIdx.x * SCAN_BLK + t;
    int v = (g < NN) ? cnt[g] : 0;
    sm[t] = v;
    __syncthreads();
    for (int off = 1; off < SCAN_BLK; off <<= 1) {
        int u = (t >= off) ? sm[t - off] : 0;
        __syncthreads();
        sm[t] += u;
        __syncthreads();
    }
    if (g < NN) row_ptr[g + 1] = sm[t];
    if (t == SCAN_BLK - 1) partials[blockIdx.x] = sm[t];
}

__global__ __launch_bounds__(64) void scan2_kernel(int* __restrict__ partials, int nb) {
    int t = threadIdx.x;
    int v = (t < nb) ? partials[t] : 0;
    int x = v;
    for (int off = 1; off < 64; off <<= 1) {
        int y = __shfl_up(x, off);
        if (t >= off) x += y;
    }
    if (t < nb) partials[t] = x - v;
}

// also zeroes cnt so scatter can reuse it (saves a memset dispatch)
__global__ __launch_bounds__(SCAN_BLK) void scan3_kernel(int* __restrict__ row_ptr,
                                                         const int* __restrict__ partials,
                                                         int* __restrict__ cnt) {
    int g = blockIdx.x * SCAN_BLK + threadIdx.x;
    if (g < NN) {
        row_ptr[g + 1] += partials[blockIdx.x];
        cnt[g] = 0;
    }
    if (g == 0) row_ptr[0] = 0;
}

__global__ __launch_bounds__(256) void scatter_kernel(const int* __restrict__ ei,
                                                      int* __restrict__ cnt,
                                                      const int* __restrict__ row_ptr,
                                                      int* __restrict__ csr_src) {
    int e = blockIdx.x * 256 + threadIdx.x;
    if (e >= ET) return;
    int src, dst;
    if (e < NE) { src = ei[e]; dst = ei[NE + e]; }
    else        { src = e - NE; dst = e - NE; }
    int pos = atomicAdd(&cnt[dst], 1);
    csr_src[row_ptr[dst] + pos] = src;
}

// ---------------------------------------------------------------------------
// fp32 -> bf16 split helpers
// ---------------------------------------------------------------------------
__device__ __forceinline__ unsigned short f2bf(float f) {
    unsigned int u = __float_as_uint(f);
    unsigned int r = (u + 0x7FFFu + ((u >> 16) & 1u)) >> 16;   // RNE
    return (unsigned short)r;
}
__device__ __forceinline__ float bf2f(unsigned short h) {
    return __uint_as_float(((unsigned int)h) << 16);
}

// ---------------------------------------------------------------------------
// Split-bf16 MFMA GEMM: C[M,N] = A[M,K] * B[N,K]^T (fp32 in, ~fp32 acc).
// BM=128, BN=64, BK=32; 256 threads = 4 waves (2x2), wave tile 64x32.
// Output fp16, optional output row stride / dual-B (for fused mu|lv GEMM).
// ---------------------------------------------------------------------------
#define LSTR 40
__device__ __forceinline__ void gemm_core(const float* __restrict__ A,
                                          const float* __restrict__ B1,
                                          const float* __restrict__ B2,
                                          __half* __restrict__ C,
                                          int M, int CS, int K) {
    __shared__ unsigned short Ah[128 * LSTR], Al[128 * LSTR];
    __shared__ unsigned short Bh[64 * LSTR],  Bl[64 * LSTR];

    const int tid  = threadIdx.x;
    const int lane = tid & 63;
    const int wid  = tid >> 6;
    const int wm   = wid & 1;
    const int wn   = wid >> 1;
    const int quad = lane >> 4;
    const int l15  = lane & 15;
    const int m0   = blockIdx.x * 128;
    const int n0   = blockIdx.y * 64;

    const int srow = tid >> 3;       // 0..31
    const int scol = (tid & 7) * 4;  // float offset

    f32x4 acc[4][2];
#pragma unroll
    for (int i = 0; i < 4; i++)
#pragma unroll
        for (int j = 0; j < 2; j++) acc[i][j] = (f32x4)(0.f);

    for (int k0 = 0; k0 < K; k0 += 32) {
#pragma unroll
        for (int p = 0; p < 4; p++) {
            int r = srow + p * 32;
            int gm = m0 + r;
            float4 v = make_float4(0.f, 0.f, 0.f, 0.f);
            if (gm < M) v = *reinterpret_cast<const float4*>(&A[(size_t)gm * K + k0 + scol]);
            unsigned short h0 = f2bf(v.x), h1 = f2bf(v.y), h2 = f2bf(v.z), h3 = f2bf(v.w);
            unsigned short g0 = f2bf(v.x - bf2f(h0)), g1 = f2bf(v.y - bf2f(h1));
            unsigned short g2 = f2bf(v.z - bf2f(h2)), g3 = f2bf(v.w - bf2f(h3));
            int off = r * LSTR + scol;
            *reinterpret_cast<uint2*>(&Ah[off]) =
                make_uint2((unsigned)h0 | ((unsigned)h1 << 16), (unsigned)h2 | ((unsigned)h3 << 16));
            *reinterpret_cast<uint2*>(&Al[off]) =
                make_uint2((unsigned)g0 | ((unsigned)g1 << 16), (unsigned)g2 | ((unsigned)g3 << 16));
        }
#pragma unroll
        for (int p = 0; p < 2; p++) {
            int r = srow + p * 32;
            int r2 = n0 + r;
            const float* Brow = (r2 < 192) ? &B1[(size_t)r2 * K] : &B2[(size_t)(r2 - 192) * K];
            float4 v = *reinterpret_cast<const float4*>(&Brow[k0 + scol]);
            unsigned short h0 = f2bf(v.x), h1 = f2bf(v.y), h2 = f2bf(v.z), h3 = f2bf(v.w);
            unsigned short g0 = f2bf(v.x - bf2f(h0)), g1 = f2bf(v.y - bf2f(h1));
            unsigned short g2 = f2bf(v.z - bf2f(h2)), g3 = f2bf(v.w - bf2f(h3));
            int off = r * LSTR + scol;
            *reinterpret_cast<uint2*>(&Bh[off]) =
                make_uint2((unsigned)h0 | ((unsigned)h1 << 16), (unsigned)h2 | ((unsigned)h3 << 16));
            *reinterpret_cast<uint2*>(&Bl[off]) =
                make_uint2((unsigned)g0 | ((unsigned)g1 << 16), (unsigned)g2 | ((unsigned)g3 << 16));
        }
        __syncthreads();

        short8 afh[4], afl[4], bfh[2], bfl[2];
#pragma unroll
        for (int tm = 0; tm < 4; tm++) {
            int off = (wm * 64 + tm * 16 + l15) * LSTR + quad * 8;
            afh[tm] = *reinterpret_cast<const short8*>(&Ah[off]);
            afl[tm] = *reinterpret_cast<const short8*>(&Al[off]);
        }
#pragma unroll
        for (int tn = 0; tn < 2; tn++) {
            int off = (wn * 32 + tn * 16 + l15) * LSTR + quad * 8;
            bfh[tn] = *reinterpret_cast<const short8*>(&Bh[off]);
            bfl[tn] = *reinterpret_cast<const short8*>(&Bl[off]);
        }
#pragma unroll
        for (int tm = 0; tm < 4; tm++)
#pragma unroll
            for (int tn = 0; tn < 2; tn++) {
                acc[tm][tn] = __builtin_amdgcn_mfma_f32_16x16x32_bf16(afh[tm], bfh[tn], acc[tm][tn], 0, 0, 0);
                acc[tm][tn] = __builtin_amdgcn_mfma_f32_16x16x32_bf16(afh[tm], bfl[tn], acc[tm][tn], 0, 0, 0);
                acc[tm][tn] = __builtin_amdgcn_mfma_f32_16x16x32_bf16(afl[tm], bfh[tn], acc[tm][tn], 0, 0, 0);
            }
        __syncthreads();
    }

#pragma unroll
    for (int tm = 0; tm < 4; tm++) {
        int rbase = m0 + wm * 64 + tm * 16 + quad * 4;
#pragma unroll
        for (int r = 0; r < 4; r++) {
            int row = rbase + r;
            if (row < M) {
#pragma unroll
                for (int tn = 0; tn < 2; tn++) {
                    int col = n0 + wn * 32 + tn * 16 + l15;
                    C[(size_t)row * CS + col] = __float2half(acc[tm][tn][r]);
                }
            }
        }
    }
}

__global__ __launch_bounds__(256) void sgemm1(const float* __restrict__ A,
                                              const float* __restrict__ B,
                                              __half* __restrict__ C) {
    gemm_core(A, B, B, C, NN, HC, FIN);      // N=192, B2 never selected
}

__global__ __launch_bounds__(256) void sgemm23(const float* __restrict__ A,
                                               const float* __restrict__ Bmu,
                                               const float* __restrict__ Blv,
                                               __half* __restrict__ C) {
    gemm_core(A, Bmu, Blv, C, NN, MLW, HC);  // N=384 = mu|lv
}

// ---------------------------------------------------------------------------
// Attention logits, layer 1 (h stride HC)
// ---------------------------------------------------------------------------
__global__ __launch_bounds__(256) void al_h_kernel(const __half* __restrict__ h,
                                                   const float* __restrict__ a_src,
                                                   const float* __restrict__ a_dst,
                                                   float* __restrict__ al_src,
                                                   float* __restrict__ al_dst) {
    int wid = (blockIdx.x * 256 + threadIdx.x) >> 6;
    int lane = threadIdx.x & 63;
    if (wid >= NN * NHEAD) return;
    int n = wid / 3;
    int head = wid - n * 3;
    float v = __half2float(h[(size_t)n * HC + head * CDIM + lane]);
    float ps = v * a_src[head * CDIM + lane];
    float pd = v * a_dst[head * CDIM + lane];
#pragma unroll
    for (int off = 32; off; off >>= 1) {
        ps += __shfl_xor(ps, off);
        pd += __shfl_xor(pd, off);
    }
    if (lane == 0) { al_src[wid] = ps; al_dst[wid] = pd; }
}

// Fused mu+lv logits from hml (stride MLW): 4 outputs in one pass.
__global__ __launch_bounds__(256) void al_ml_kernel(const __half* __restrict__ hml,
                                                    const float* __restrict__ amus,
                                                    const float* __restrict__ amud,
                                                    const float* __restrict__ alvs,
                                                    const float* __restrict__ alvd,
                                                    float* __restrict__ alms,
                                                    float* __restrict__ almd,
                                                    float* __restrict__ alls,
                                                    float* __restrict__ alld) {
    int wid = (blockIdx.x * 256 + threadIdx.x) >> 6;
    int lane = threadIdx.x & 63;
    if (wid >= NN * NHEAD) return;
    int n = wid / 3;
    int head = wid - n * 3;
    int c = head * CDIM + lane;
    float vm = __half2float(hml[(size_t)n * MLW + c]);
    float vl = __half2float(hml[(size_t)n * MLW + 192 + c]);
    float ms = vm * amus[c], md = vm * amud[c];
    float ls = vl * alvs[c], ld = vl * alvd[c];
#pragma unroll
    for (int off = 32; off; off >>= 1) {
        ms += __shfl_xor(ms, off);
        md += __shfl_xor(md, off);
        ls += __shfl_xor(ls, off);
        ld += __shfl_xor(ld, off);
    }
    if (lane == 0) { alms[wid] = ms; almd[wid] = md; alls[wid] = ls; alld[wid] = ld; }
}

// ---------------------------------------------------------------------------
// Per-wave softmax weights into LDS; returns softmax denominator.
// ---------------------------------------------------------------------------
__device__ __forceinline__ float edge_weights(const int* slds3, float* wrow,
                                              const float* __restrict__ al_s,
                                              float ad, int head, int deg, int lane) {
    float m = -1e30f;
    for (int j = lane; j < deg; j += 64) {
        float a = al_s[slds3[j] + head] + ad;
        a = a > 0.f ? a : 0.2f * a;
        wrow[j] = a;
        m = fmaxf(m, a);
    }
#pragma unroll
    for (int off = 32; off; off >>= 1) m = fmaxf(m, __shfl_xor(m, off));
    float ssum = 0.f;
    for (int j = lane; j < deg; j += 64) {
        float w = __expf(wrow[j] - m);
        wrow[j] = w;
        ssum += w;
    }
#pragma unroll
    for (int off = 32; off; off >>= 1) ssum += __shfl_xor(ssum, off);
    return ssum;
}

// ---------------------------------------------------------------------------
// v_fma_mix_f32: acc += (f32)(fp16 half of u) * w  in ONE VALU op.
// Bit-identical to cvt+fma (fp16->fp32 is exact; same fp32 fma), but halves
// the gather-loop VALU issue count (8 -> 4 ops per uint2).
// ---------------------------------------------------------------------------
__device__ __forceinline__ float4 fma4h(float w, uint2 u, float4 acc) {
    asm("v_fma_mix_f32 %0, %1, %2, %0 op_sel:[0,0,0] op_sel_hi:[1,0,0]"
        : "+v"(acc.x) : "v"(u.x), "v"(w));
    asm("v_fma_mix_f32 %0, %1, %2, %0 op_sel:[1,0,0] op_sel_hi:[1,0,0]"
        : "+v"(acc.y) : "v"(u.x), "v"(w));
    asm("v_fma_mix_f32 %0, %1, %2, %0 op_sel:[0,0,0] op_sel_hi:[1,0,0]"
        : "+v"(acc.z) : "v"(u.y), "v"(w));
    asm("v_fma_mix_f32 %0, %1, %2, %0 op_sel:[1,0,0] op_sel_hi:[1,0,0]"
        : "+v"(acc.w) : "v"(u.y), "v"(w));
    return acc;
}

// ---------------------------------------------------------------------------
// Layer-1 aggregation (concat + bias + relu). 3 waves/node, fp16 h.
// 16 edges/iter: 4 independent gather loads in flight.
// ---------------------------------------------------------------------------
__global__ __launch_bounds__(192) void agg_cat_kernel(const int* __restrict__ row_ptr,
                                                      const int* __restrict__ csr_src,
                                                      const __half* __restrict__ h,
                                                      const float* __restrict__ al_src,
                                                      const float* __restrict__ al_dst,
                                                      const float* __restrict__ bias,
                                                      float* __restrict__ out) {
    __shared__ int slds3[MAXDEG];
    __shared__ int sldsHC[MAXDEG];
    __shared__ float wlds[3][MAXDEG];
    int n = blockIdx.x;
    int head = threadIdx.x >> 6;
    int lane = threadIdx.x & 63;
    int start = row_ptr[n];
    int deg = row_ptr[n + 1] - start;
    float ad = al_dst[n * 3 + head];

    if (deg <= MAXDEG) {
        if (threadIdx.x < deg) {
            int s = csr_src[start + threadIdx.x];
            slds3[threadIdx.x] = s * 3;
            sldsHC[threadIdx.x] = s * HC;
        }
        __syncthreads();
        float ssum = edge_weights(slds3, wlds[head], al_src, ad, head, deg, lane);
        const int sub = lane >> 4, l16 = lane & 15;
        const int hoff = head * CDIM + l16 * 4;
        const float* wrow = wlds[head];
        float4 acc = make_float4(0.f, 0.f, 0.f, 0.f);
        int j = 0;
        for (; j + 16 <= deg; j += 16) {
            int s0 = sldsHC[j + sub],      s1 = sldsHC[j + 4 + sub];
            int s2 = sldsHC[j + 8 + sub],  s3 = sldsHC[j + 12 + sub];
            float w0 = wrow[j + sub],      w1 = wrow[j + 4 + sub];
            float w2 = wrow[j + 8 + sub],  w3 = wrow[j + 12 + sub];
            uint2 u0 = *reinterpret_cast<const uint2*>(&h[s0 + hoff]);
            uint2 u1 = *reinterpret_cast<const uint2*>(&h[s1 + hoff]);
            uint2 u2 = *reinterpret_cast<const uint2*>(&h[s2 + hoff]);
            uint2 u3 = *reinterpret_cast<const uint2*>(&h[s3 + hoff]);
            acc = fma4h(w0, u0, acc); acc = fma4h(w1, u1, acc);
            acc = fma4h(w2, u2, acc); acc = fma4h(w3, u3, acc);
        }
        for (; j + 4 <= deg; j += 4) {
            int s = sldsHC[j + sub];
            float w = wrow[j + sub];
            uint2 u = *reinterpret_cast<const uint2*>(&h[s + hoff]);
            acc = fma4h(w, u, acc);
        }
        if (sub < deg - j) {
            int s = sldsHC[j + sub];
            float w = wrow[j + sub];
            uint2 u = *reinterpret_cast<const uint2*>(&h[s + hoff]);
            acc = fma4h(w, u, acc);
        }
#pragma unroll
        for (int off = 16; off <= 32; off <<= 1) {
            acc.x += __shfl_xor(acc.x, off);
            acc.y += __shfl_xor(acc.y, off);
            acc.z += __shfl_xor(acc.z, off);
            acc.w += __shfl_xor(acc.w, off);
        }
        if (lane < 16) {
            float inv = 1.f / (ssum + 1e-16f);
            const float4 b4 = *reinterpret_cast<const float4*>(&bias[head * CDIM + l16 * 4]);
            float4 o;
            o.x = fmaxf(fmaf(acc.x, inv, b4.x), 0.f);
            o.y = fmaxf(fmaf(acc.y, inv, b4.y), 0.f);
            o.z = fmaxf(fmaf(acc.z, inv, b4.z), 0.f);
            o.w = fmaxf(fmaf(acc.w, inv, b4.w), 0.f);
            *reinterpret_cast<float4*>(&out[(size_t)n * HC + head * CDIM + l16 * 4]) = o;
        }
    } else {  // streaming fallback (not hit for this graph; correctness-safe)
        float m = -1e30f;
        for (int j = start + lane; j < start + deg; j += 64) {
            float a = al_src[csr_src[j] * 3 + head] + ad;
            a = a > 0.f ? a : 0.2f * a;
            m = fmaxf(m, a);
        }
#pragma unroll
        for (int off = 32; off; off >>= 1) m = fmaxf(m, __shfl_xor(m, off));
        float acc = 0.f, ssum = 0.f;
        for (int j = start; j < start + deg; ++j) {
            int s = csr_src[j];
            float a = al_src[s * 3 + head] + ad;
            a = a > 0.f ? a : 0.2f * a;
            float w = __expf(a - m);
            ssum += w;
            acc = fmaf(w, __half2float(h[(size_t)s * HC + head * CDIM + lane]), acc);
        }
        float o = acc / (ssum + 1e-16f) + bias[head * CDIM + lane];
        out[(size_t)n * HC + head * CDIM + lane] = fmaxf(o, 0.f);
    }
}

// ---------------------------------------------------------------------------
// mu/lv aggregation fused over interleaved hml[n][384]: 3 waves/node, each
// wave = one head, both mu & lv; 16 edges/iter -> 8 loads in flight.
// ---------------------------------------------------------------------------
__global__ __launch_bounds__(192) void agg_mean2_kernel(const int* __restrict__ row_ptr,
                                                        const int* __restrict__ csr_src,
                                                        const __half* __restrict__ hml,
                                                        const float* __restrict__ alms,
                                                        const float* __restrict__ almd,
                                                        const float* __restrict__ alls,
                                                        const float* __restrict__ alld,
                                                        const float* __restrict__ b_mu,
                                                        const float* __restrict__ b_lv,
                                                        float* __restrict__ out) {
    __shared__ int slds3[MAXDEG];
    __shared__ int sldsML[MAXDEG];
    __shared__ float wm_[3][MAXDEG], wl_[3][MAXDEG];
    __shared__ __align__(16) float red[6][64];
    int n = blockIdx.x;
    int head = threadIdx.x >> 6;   // 0..2
    int lane = threadIdx.x & 63;
    int start = row_ptr[n];
    int deg = row_ptr[n + 1] - start;
    float adm = almd[n * 3 + head];
    float adl = alld[n * 3 + head];

    if (deg <= MAXDEG) {
        if (threadIdx.x < deg) {
            int s = csr_src[start + threadIdx.x];
            slds3[threadIdx.x] = s * 3;
            sldsML[threadIdx.x] = s * MLW;
        }
        __syncthreads();
        // softmax weights for mu and lv, interleaved
        float mm = -1e30f, ml = -1e30f;
        for (int j = lane; j < deg; j += 64) {
            int idx = slds3[j] + head;
            float am = alms[idx] + adm;
            float av = alls[idx] + adl;
            am = am > 0.f ? am : 0.2f * am;
            av = av > 0.f ? av : 0.2f * av;
            wm_[head][j] = am; wl_[head][j] = av;
            mm = fmaxf(mm, am); ml = fmaxf(ml, av);
        }
#pragma unroll
        for (int off = 32; off; off >>= 1) {
            mm = fmaxf(mm, __shfl_xor(mm, off));
            ml = fmaxf(ml, __shfl_xor(ml, off));
        }
        float sm = 0.f, sl = 0.f;
        for (int j = lane; j < deg; j += 64) {
            float em = __expf(wm_[head][j] - mm); wm_[head][j] = em; sm += em;
            float el = __expf(wl_[head][j] - ml); wl_[head][j] = el; sl += el;
        }
#pragma unroll
        for (int off = 32; off; off >>= 1) {
            sm += __shfl_xor(sm, off);
            sl += __shfl_xor(sl, off);
        }
        // joint gather: 8 loads in flight per iteration
        const int sub = lane >> 4, l16 = lane & 15;
        const int hoffm = head * CDIM + l16 * 4;
        const int hoffl = hoffm + 192;
        float4 am4 = make_float4(0.f, 0.f, 0.f, 0.f);
        float4 al4 = make_float4(0.f, 0.f, 0.f, 0.f);
        int j = 0;
        for (; j + 16 <= deg; j += 16) {
            int s0 = sldsML[j + sub],     s1 = sldsML[j + 4 + sub];
            int s2 = sldsML[j + 8 + sub], s3 = sldsML[j + 12 + sub];
            float wm0 = wm_[head][j + sub],      wm1 = wm_[head][j + 4 + sub];
            float wm2 = wm_[head][j + 8 + sub],  wm3 = wm_[head][j + 12 + sub];
            float wl0 = wl_[head][j + sub],      wl1 = wl_[head][j + 4 + sub];
            float wl2 = wl_[head][j + 8 + sub],  wl3 = wl_[head][j + 12 + sub];
            uint2 uM0 = *reinterpret_cast<const uint2*>(&hml[s0 + hoffm]);
            uint2 uL0 = *reinterpret_cast<const uint2*>(&hml[s0 + hoffl]);
            uint2 uM1 = *reinterpret_cast<const uint2*>(&hml[s1 + hoffm]);
            uint2 uL1 = *reinterpret_cast<const uint2*>(&hml[s1 + hoffl]);
            uint2 uM2 = *reinterpret_cast<const uint2*>(&hml[s2 + hoffm]);
            uint2 uL2 = *reinterpret_cast<const uint2*>(&hml[s2 + hoffl]);
            uint2 uM3 = *reinterpret_cast<const uint2*>(&hml[s3 + hoffm]);
            uint2 uL3 = *reinterpret_cast<const uint2*>(&hml[s3 + hoffl]);
            am4 = fma4h(wm0, uM0, am4); al4 = fma4h(wl0, uL0, al4);
            am4 = fma4h(wm1, uM1, am4); al4 = fma4h(wl1, uL1, al4);
            am4 = fma4h(wm2, uM2, am4); al4 = fma4h(wl2, uL2, al4);
            am4 = fma4h(wm3, uM3, am4); al4 = fma4h(wl3, uL3, al4);
        }
        for (; j + 4 <= deg; j += 4) {
            int s = sldsML[j + sub];
            float wmA = wm_[head][j + sub], wlA = wl_[head][j + sub];
            uint2 uM = *reinterpret_cast<const uint2*>(&hml[s + hoffm]);
            uint2 uL = *reinterpret_cast<const uint2*>(&hml[s + hoffl]);
            am4 = fma4h(wmA, uM, am4); al4 = fma4h(wlA, uL, al4);
        }
        if (sub < deg - j) {
            int s = sldsML[j + sub];
            float wmA = wm_[head][j + sub], wlA = wl_[head][j + sub];
            uint2 uM = *reinterpret_cast<const uint2*>(&hml[s + hoffm]);
            uint2 uL = *reinterpret_cast<const uint2*>(&hml[s + hoffl]);
            am4 = fma4h(wmA, uM, am4); al4 = fma4h(wlA, uL, al4);
        }
#pragma unroll
        for (int off = 16; off <= 32; off <<= 1) {
            am4.x += __shfl_xor(am4.x, off); am4.y += __shfl_xor(am4.y, off);
            am4.z += __shfl_xor(am4.z, off); am4.w += __shfl_xor(am4.w, off);
            al4.x += __shfl_xor(al4.x, off); al4.y += __shfl_xor(al4.y, off);
            al4.z += __shfl_xor(al4.z, off); al4.w += __shfl_xor(al4.w, off);
        }
        if (lane < 16) {
            float invm = 1.f / (sm + 1e-16f);
            float invl = 1.f / (sl + 1e-16f);
            float4 rm, rl;
            rm.x = am4.x * invm; rm.y = am4.y * invm; rm.z = am4.z * invm; rm.w = am4.w * invm;
            rl.x = al4.x * invl; rl.y = al4.y * invl; rl.z = al4.z * invl; rl.w = al4.w * invl;
            *reinterpret_cast<float4*>(&red[head][l16 * 4]) = rm;
            *reinterpret_cast<float4*>(&red[3 + head][l16 * 4]) = rl;
        }
    } else {  // streaming fallback (not hit; correctness-safe)
        for (int pass = 0; pass < 2; ++pass) {
            const float* as = pass ? alls : alms;
            float ad = pass ? adl : adm;
            int coff = pass ? 192 : 0;
            float m = -1e30f;
            for (int j = start + lane; j < start + deg; j += 64) {
                float a = as[csr_src[j] * 3 + head] + ad;
                a = a > 0.f ? a : 0.2f * a;
                m = fmaxf(m, a);
            }
#pragma unroll
            for (int off = 32; off; off >>= 1) m = fmaxf(m, __shfl_xor(m, off));
            float acc = 0.f, ssum = 0.f;
            for (int j = start; j < start + deg; ++j) {
                int s = csr_src[j];
                float a = as[s * 3 + head] + ad;
                a = a > 0.f ? a : 0.2f * a;
                float w = __expf(a - m);
                ssum += w;
                acc = fmaf(w, __half2float(hml[(size_t)s * MLW + coff + head * CDIM + lane]), acc);
            }
            red[pass * 3 + head][lane] = acc / (ssum + 1e-16f);
        }
    }
    __syncthreads();
    if (threadIdx.x < 64) {
        out[(size_t)n * CDIM + lane] =
            (red[0][lane] + red[1][lane] + red[2][lane]) * (1.f / 3.f) + b_mu[lane];
    } else if (threadIdx.x < 128) {
        out[(size_t)NN * CDIM + (size_t)n * CDIM + lane] =
            (red[3][lane] + red[4][lane] + red[5][lane]) * (1.f / 3.f) + b_lv[lane];
    }
}

// ---------------------------------------------------------------------------
extern "C" void kernel_launch(void* const* d_in, const int* in_sizes, int n_in,
                              void* d_out, int out_size, void* d_ws, size_t ws_size,
                              hipStream_t stream) {
    const float* x    = (const float*)d_in[0];
    const int*   ei   = (const int*)d_in[1];
    const float* W1   = (const float*)d_in[2];
    const float* a1s  = (const float*)d_in[3];
    const float* a1d  = (const float*)d_in[4];
    const float* b1   = (const float*)d_in[5];
    const float* Wmu  = (const float*)d_in[6];
    const float* amus = (const float*)d_in[7];
    const float* amud = (const float*)d_in[8];
    const float* bmu  = (const float*)d_in[9];
    const float* Wlv  = (const float*)d_in[10];
    const float* alvs = (const float*)d_in[11];
    const float* alvd = (const float*)d_in[12];
    const float* blv  = (const float*)d_in[13];
    float* out = (float*)d_out;

    // workspace carve (256B aligned)
    size_t off = 0;
    auto carve = [&](size_t bytes) {
        void* p = (char*)d_ws + off;
        off += (bytes + 255) & ~(size_t)255;
        return p;
    };
    int*    cnt      = (int*)carve((size_t)NN * 4);
    int*    row_ptr  = (int*)carve((size_t)(NN + 1) * 4);
    int*    partials = (int*)carve(64 * 4);
    int*    csr      = (int*)carve((size_t)ET * 4);
    __half* h1f16    = (__half*)carve((size_t)NN * HC * 2);
    float*  hrelu    = (float*)carve((size_t)NN * HC * 4);
    __half* hml      = (__half*)carve((size_t)NN * MLW * 2);
    float*  al1s     = (float*)carve((size_t)NN * 3 * 4);
    float*  al1d     = (float*)carve((size_t)NN * 3 * 4);
    float*  alms     = (float*)carve((size_t)NN * 3 * 4);
    float*  almd     = (float*)carve((size_t)NN * 3 * 4);
    float*  alls     = (float*)carve((size_t)NN * 3 * 4);
    float*  alld     = (float*)carve((size_t)NN * 3 * 4);

    const int scan_blocks = (NN + SCAN_BLK - 1) / SCAN_BLK;  // 49

    // ---- CSR build (shared by all 3 layers) ----
    hipMemsetAsync(cnt, 0, (size_t)NN * 4, stream);
    hist_kernel<<<(ET + 255) / 256, 256, 0, stream>>>(ei, cnt);
    scan1_kernel<<<scan_blocks, SCAN_BLK, 0, stream>>>(cnt, row_ptr, partials);
    scan2_kernel<<<1, 64, 0, stream>>>(partials, scan_blocks);
    scan3_kernel<<<scan_blocks, SCAN_BLK, 0, stream>>>(row_ptr, partials, cnt);
    scatter_kernel<<<(ET + 255) / 256, 256, 0, stream>>>(ei, cnt, row_ptr, csr);

    // ---- Layer 1 (fp16 h) ----
    dim3 g1((NN + 127) / 128, HC / 64);
    sgemm1<<<g1, 256, 0, stream>>>(x, W1, h1f16);
    al_h_kernel<<<(NN * 3 + 3) / 4, 256, 0, stream>>>(h1f16, a1s, a1d, al1s, al1d);
    agg_cat_kernel<<<NN, 192, 0, stream>>>(row_ptr, csr, h1f16, al1s, al1d, b1, hrelu);

    // ---- Layers mu / lv fused: one GEMM (N=384), one al pass ----
    dim3 g2((NN + 127) / 128, MLW / 64);
    sgemm23<<<g2, 256, 0, stream>>>(hrelu, Wmu, Wlv, hml);
    al_ml_kernel<<<(NN * 3 + 3) / 4, 256, 0, stream>>>(hml, amus, amud, alvs, alvd,
                                                       alms, almd, alls, alld);
    agg_mean2_kernel<<<NN, 192, 0, stream>>>(row_ptr, csr, hml,
                                             alms, almd, alls, alld, bmu, blv, out);
}

// Round 4
// 508.568 us; speedup vs baseline: 1.0929x; 1.0390x over previous
//
#include <hip/hip_runtime.h>
#include <hip/hip_bf16.h>
#include <hip/hip_fp16.h>

// Problem constants (from reference)
#define NN 50000
#define NE 800000
#define ET (NE + NN)          // edges + self loops = 850000
#define FIN 256
#define HC 192                // H*C = 3*64
#define NHEAD 3
#define CDIM 64
#define MAXDEG 128            // fast-path cap; Poisson(17) max over 50K nodes ~45
#define MLW 384               // hml row width (mu 0..191 | lv 192..383)

typedef short short8 __attribute__((ext_vector_type(8)));
typedef float f32x4 __attribute__((ext_vector_type(4)));

// ---------------------------------------------------------------------------
// CSR build: histogram -> scan -> scatter (graph shared by all 3 GAT layers)
// ---------------------------------------------------------------------------
__global__ __launch_bounds__(256) void hist_kernel(const int* __restrict__ ei,
                                                   int* __restrict__ cnt) {
    int e = blockIdx.x * 256 + threadIdx.x;
    if (e >= ET) return;
    int dst = (e < NE) ? ei[NE + e] : (e - NE);
    atomicAdd(&cnt[dst], 1);
}

#define SCAN_BLK 1024
__global__ __launch_bounds__(SCAN_BLK) void scan1_kernel(const int* __restrict__ cnt,
                                                         int* __restrict__ row_ptr,
                                                         int* __restrict__ partials) {
    __shared__ int sm[SCAN_BLK];
    int t = threadIdx.x;
    int g = blockIdx.x * SCAN_BLK + t;
    int v = (g < NN) ? cnt[g] : 0;
    sm[t] = v;
    __syncthreads();
    for (int off = 1; off < SCAN_BLK; off <<= 1) {
        int u = (t >= off) ? sm[t - off] : 0;
        __syncthreads();
        sm[t] += u;
        __syncthreads();
    }
    if (g < NN) row_ptr[g + 1] = sm[t];
    if (t == SCAN_BLK - 1) partials[blockIdx.x] = sm[t];
}

__global__ __launch_bounds__(64) void scan2_kernel(int* __restrict__ partials, int nb) {
    int t = threadIdx.x;
    int v = (t < nb) ? partials[t] : 0;
    int x = v;
    for (int off = 1; off < 64; off <<= 1) {
        int y = __shfl_up(x, off);
        if (t >= off) x += y;
    }
    if (t < nb) partials[t] = x - v;
}

// also zeroes cnt so scatter can reuse it (saves a memset dispatch)
__global__ __launch_bounds__(SCAN_BLK) void scan3_kernel(int* __restrict__ row_ptr,
                                                         const int* __restrict__ partials,
                                                         int* __restrict__ cnt) {
    int g = blockIdx.x * SCAN_BLK + threadIdx.x;
    if (g < NN) {
        row_ptr[g + 1] += partials[blockIdx.x];
        cnt[g] = 0;
    }
    if (g == 0) row_ptr[0] = 0;
}

__global__ __launch_bounds__(256) void scatter_kernel(const int* __restrict__ ei,
                                                      int* __restrict__ cnt,
                                                      const int* __restrict__ row_ptr,
                                                      int* __restrict__ csr_src) {
    int e = blockIdx.x * 256 + threadIdx.x;
    if (e >= ET) return;
    int src, dst;
    if (e < NE) { src = ei[e]; dst = ei[NE + e]; }
    else        { src = e - NE; dst = e - NE; }
    int pos = atomicAdd(&cnt[dst], 1);
    csr_src[row_ptr[dst] + pos] = src;
}

// ---------------------------------------------------------------------------
// fp32 -> bf16 split helpers
// ---------------------------------------------------------------------------
__device__ __forceinline__ unsigned short f2bf(float f) {
    unsigned int u = __float_as_uint(f);
    unsigned int r = (u + 0x7FFFu + ((u >> 16) & 1u)) >> 16;   // RNE
    return (unsigned short)r;
}
__device__ __forceinline__ float bf2f(unsigned short h) {
    return __uint_as_float(((unsigned int)h) << 16);
}

// ---------------------------------------------------------------------------
// Split-bf16 MFMA GEMM: C[M,N] = A[M,K] * B[N,K]^T (fp32 in, ~fp32 acc).
// BM=128, BN=64, BK=32; 256 threads = 4 waves (2x2), wave tile 64x32.
// Output fp16, optional output row stride / dual-B (for fused mu|lv GEMM).
// ---------------------------------------------------------------------------
#define LSTR 40
__device__ __forceinline__ void gemm_core(const float* __restrict__ A,
                                          const float* __restrict__ B1,
                                          const float* __restrict__ B2,
                                          __half* __restrict__ C,
                                          int M, int CS, int K) {
    __shared__ unsigned short Ah[128 * LSTR], Al[128 * LSTR];
    __shared__ unsigned short Bh[64 * LSTR],  Bl[64 * LSTR];

    const int tid  = threadIdx.x;
    const int lane = tid & 63;
    const int wid  = tid >> 6;
    const int wm   = wid & 1;
    const int wn   = wid >> 1;
    const int quad = lane >> 4;
    const int l15  = lane & 15;
    const int m0   = blockIdx.x * 128;
    const int n0   = blockIdx.y * 64;

    const int srow = tid >> 3;       // 0..31
    const int scol = (tid & 7) * 4;  // float offset

    f32x4 acc[4][2];
#pragma unroll
    for (int i = 0; i < 4; i++)
#pragma unroll
        for (int j = 0; j < 2; j++) acc[i][j] = (f32x4)(0.f);

    for (int k0 = 0; k0 < K; k0 += 32) {
#pragma unroll
        for (int p = 0; p < 4; p++) {
            int r = srow + p * 32;
            int gm = m0 + r;
            float4 v = make_float4(0.f, 0.f, 0.f, 0.f);
            if (gm < M) v = *reinterpret_cast<const float4*>(&A[(size_t)gm * K + k0 + scol]);
            unsigned short h0 = f2bf(v.x), h1 = f2bf(v.y), h2 = f2bf(v.z), h3 = f2bf(v.w);
            unsigned short g0 = f2bf(v.x - bf2f(h0)), g1 = f2bf(v.y - bf2f(h1));
            unsigned short g2 = f2bf(v.z - bf2f(h2)), g3 = f2bf(v.w - bf2f(h3));
            int off = r * LSTR + scol;
            *reinterpret_cast<uint2*>(&Ah[off]) =
                make_uint2((unsigned)h0 | ((unsigned)h1 << 16), (unsigned)h2 | ((unsigned)h3 << 16));
            *reinterpret_cast<uint2*>(&Al[off]) =
                make_uint2((unsigned)g0 | ((unsigned)g1 << 16), (unsigned)g2 | ((unsigned)g3 << 16));
        }
#pragma unroll
        for (int p = 0; p < 2; p++) {
            int r = srow + p * 32;
            int r2 = n0 + r;
            const float* Brow = (r2 < 192) ? &B1[(size_t)r2 * K] : &B2[(size_t)(r2 - 192) * K];
            float4 v = *reinterpret_cast<const float4*>(&Brow[k0 + scol]);
            unsigned short h0 = f2bf(v.x), h1 = f2bf(v.y), h2 = f2bf(v.z), h3 = f2bf(v.w);
            unsigned short g0 = f2bf(v.x - bf2f(h0)), g1 = f2bf(v.y - bf2f(h1));
            unsigned short g2 = f2bf(v.z - bf2f(h2)), g3 = f2bf(v.w - bf2f(h3));
            int off = r * LSTR + scol;
            *reinterpret_cast<uint2*>(&Bh[off]) =
                make_uint2((unsigned)h0 | ((unsigned)h1 << 16), (unsigned)h2 | ((unsigned)h3 << 16));
            *reinterpret_cast<uint2*>(&Bl[off]) =
                make_uint2((unsigned)g0 | ((unsigned)g1 << 16), (unsigned)g2 | ((unsigned)g3 << 16));
        }
        __syncthreads();

        short8 afh[4], afl[4], bfh[2], bfl[2];
#pragma unroll
        for (int tm = 0; tm < 4; tm++) {
            int off = (wm * 64 + tm * 16 + l15) * LSTR + quad * 8;
            afh[tm] = *reinterpret_cast<const short8*>(&Ah[off]);
            afl[tm] = *reinterpret_cast<const short8*>(&Al[off]);
        }
#pragma unroll
        for (int tn = 0; tn < 2; tn++) {
            int off = (wn * 32 + tn * 16 + l15) * LSTR + quad * 8;
            bfh[tn] = *reinterpret_cast<const short8*>(&Bh[off]);
            bfl[tn] = *reinterpret_cast<const short8*>(&Bl[off]);
        }
#pragma unroll
        for (int tm = 0; tm < 4; tm++)
#pragma unroll
            for (int tn = 0; tn < 2; tn++) {
                acc[tm][tn] = __builtin_amdgcn_mfma_f32_16x16x32_bf16(afh[tm], bfh[tn], acc[tm][tn], 0, 0, 0);
                acc[tm][tn] = __builtin_amdgcn_mfma_f32_16x16x32_bf16(afh[tm], bfl[tn], acc[tm][tn], 0, 0, 0);
                acc[tm][tn] = __builtin_amdgcn_mfma_f32_16x16x32_bf16(afl[tm], bfh[tn], acc[tm][tn], 0, 0, 0);
            }
        __syncthreads();
    }

#pragma unroll
    for (int tm = 0; tm < 4; tm++) {
        int rbase = m0 + wm * 64 + tm * 16 + quad * 4;
#pragma unroll
        for (int r = 0; r < 4; r++) {
            int row = rbase + r;
            if (row < M) {
#pragma unroll
                for (int tn = 0; tn < 2; tn++) {
                    int col = n0 + wn * 32 + tn * 16 + l15;
                    C[(size_t)row * CS + col] = __float2half(acc[tm][tn][r]);
                }
            }
        }
    }
}

__global__ __launch_bounds__(256) void sgemm1(const float* __restrict__ A,
                                              const float* __restrict__ B,
                                              __half* __restrict__ C) {
    gemm_core(A, B, B, C, NN, HC, FIN);      // N=192, B2 never selected
}

__global__ __launch_bounds__(256) void sgemm23(const float* __restrict__ A,
                                               const float* __restrict__ Bmu,
                                               const float* __restrict__ Blv,
                                               __half* __restrict__ C) {
    gemm_core(A, Bmu, Blv, C, NN, MLW, HC);  // N=384 = mu|lv
}

// ---------------------------------------------------------------------------
// Attention logits, layer 1 (h stride HC)
// ---------------------------------------------------------------------------
__global__ __launch_bounds__(256) void al_h_kernel(const __half* __restrict__ h,
                                                   const float* __restrict__ a_src,
                                                   const float* __restrict__ a_dst,
                                                   float* __restrict__ al_src,
                                                   float* __restrict__ al_dst) {
    int wid = (blockIdx.x * 256 + threadIdx.x) >> 6;
    int lane = threadIdx.x & 63;
    if (wid >= NN * NHEAD) return;
    int n = wid / 3;
    int head = wid - n * 3;
    float v = __half2float(h[(size_t)n * HC + head * CDIM + lane]);
    float ps = v * a_src[head * CDIM + lane];
    float pd = v * a_dst[head * CDIM + lane];
#pragma unroll
    for (int off = 32; off; off >>= 1) {
        ps += __shfl_xor(ps, off);
        pd += __shfl_xor(pd, off);
    }
    if (lane == 0) { al_src[wid] = ps; al_dst[wid] = pd; }
}

// Fused mu+lv logits from hml (stride MLW): 4 outputs in one pass.
__global__ __launch_bounds__(256) void al_ml_kernel(const __half* __restrict__ hml,
                                                    const float* __restrict__ amus,
                                                    const float* __restrict__ amud,
                                                    const float* __restrict__ alvs,
                                                    const float* __restrict__ alvd,
                                                    float* __restrict__ alms,
                                                    float* __restrict__ almd,
                                                    float* __restrict__ alls,
                                                    float* __restrict__ alld) {
    int wid = (blockIdx.x * 256 + threadIdx.x) >> 6;
    int lane = threadIdx.x & 63;
    if (wid >= NN * NHEAD) return;
    int n = wid / 3;
    int head = wid - n * 3;
    int c = head * CDIM + lane;
    float vm = __half2float(hml[(size_t)n * MLW + c]);
    float vl = __half2float(hml[(size_t)n * MLW + 192 + c]);
    float ms = vm * amus[c], md = vm * amud[c];
    float ls = vl * alvs[c], ld = vl * alvd[c];
#pragma unroll
    for (int off = 32; off; off >>= 1) {
        ms += __shfl_xor(ms, off);
        md += __shfl_xor(md, off);
        ls += __shfl_xor(ls, off);
        ld += __shfl_xor(ld, off);
    }
    if (lane == 0) { alms[wid] = ms; almd[wid] = md; alls[wid] = ls; alld[wid] = ld; }
}

// ---------------------------------------------------------------------------
// v_fma_mix_f32: acc += (f32)(fp16 half of u) * w  in ONE VALU op.
// (compiler also pattern-matches this; kept explicit for determinism)
// ---------------------------------------------------------------------------
__device__ __forceinline__ float4 fma4h(float w, uint2 u, float4 acc) {
    asm("v_fma_mix_f32 %0, %1, %2, %0 op_sel:[0,0,0] op_sel_hi:[1,0,0]"
        : "+v"(acc.x) : "v"(u.x), "v"(w));
    asm("v_fma_mix_f32 %0, %1, %2, %0 op_sel:[1,0,0] op_sel_hi:[1,0,0]"
        : "+v"(acc.y) : "v"(u.x), "v"(w));
    asm("v_fma_mix_f32 %0, %1, %2, %0 op_sel:[0,0,0] op_sel_hi:[1,0,0]"
        : "+v"(acc.z) : "v"(u.y), "v"(w));
    asm("v_fma_mix_f32 %0, %1, %2, %0 op_sel:[1,0,0] op_sel_hi:[1,0,0]"
        : "+v"(acc.w) : "v"(u.y), "v"(w));
    return acc;
}

// ---------------------------------------------------------------------------
// Layer-1 aggregation (concat + bias + relu). 3 waves/node, fp16 h.
// T14 async-split: gather loads for edges [0,32) issued BEFORE the softmax
// phase (addresses depend only on staged indices) -> HBM latency hides under
// softmax's loads/exp/reduce. Bit-identical accumulation order.
// ---------------------------------------------------------------------------
__global__ __launch_bounds__(192) void agg_cat_kernel(const int* __restrict__ row_ptr,
                                                      const int* __restrict__ csr_src,
                                                      const __half* __restrict__ h,
                                                      const float* __restrict__ al_src,
                                                      const float* __restrict__ al_dst,
                                                      const float* __restrict__ bias,
                                                      float* __restrict__ out) {
    __shared__ int slds3[MAXDEG];
    __shared__ int sldsHC[MAXDEG];
    __shared__ float wlds[3][MAXDEG];
    int n = blockIdx.x;
    int head = threadIdx.x >> 6;
    int lane = threadIdx.x & 63;
    int start = row_ptr[n];
    int deg = row_ptr[n + 1] - start;
    float ad = al_dst[n * 3 + head];

    if (deg <= MAXDEG) {
        if (threadIdx.x < deg) {
            int s = csr_src[start + threadIdx.x];
            slds3[threadIdx.x] = s * 3;
            sldsHC[threadIdx.x] = s * HC;
        }
        __syncthreads();
        const int sub = lane >> 4, l16 = lane & 15;
        const int hoff = head * CDIM + l16 * 4;

        // phase 1: attention-logit loads (issued first so softmax's waitcnt
        // does not drain the gather preloads below)
        float ar0 = -1e30f, ar1 = -1e30f;
        if (lane < deg)      ar0 = al_src[slds3[lane] + head] + ad;
        if (lane + 64 < deg) ar1 = al_src[slds3[lane + 64] + head] + ad;

        // phase 2: issue gather preloads for edges [0,32) into registers
        uint2 pU[8];
#pragma unroll
        for (int t = 0; t < 8; ++t) {
            int e = (t >> 2) * 16 + (t & 3) * 4 + sub;
            pU[t] = make_uint2(0u, 0u);
            if (e < deg) pU[t] = *reinterpret_cast<const uint2*>(&h[sldsHC[e] + hoff]);
        }
        __builtin_amdgcn_sched_barrier(0);   // pin load issue above softmax

        // phase 3: softmax (VALU + LDS + shfl only; gather loads in flight)
        float a0 = ar0 > 0.f ? ar0 : 0.2f * ar0;
        float a1 = ar1 > 0.f ? ar1 : 0.2f * ar1;
        float m = fmaxf(a0, a1);
#pragma unroll
        for (int off = 32; off; off >>= 1) m = fmaxf(m, __shfl_xor(m, off));
        float ssum = 0.f;
        if (lane < deg)      { float e0 = __expf(a0 - m); wlds[head][lane] = e0;      ssum += e0; }
        if (lane + 64 < deg) { float e1 = __expf(a1 - m); wlds[head][lane + 64] = e1; ssum += e1; }
#pragma unroll
        for (int off = 32; off; off >>= 1) ssum += __shfl_xor(ssum, off);

        // phase 4: fma with preloaded values (same edge order as before)
        const float* wrow = wlds[head];
        float4 acc = make_float4(0.f, 0.f, 0.f, 0.f);
#pragma unroll
        for (int t = 0; t < 8; ++t) {
            int e = (t >> 2) * 16 + (t & 3) * 4 + sub;
            float w = (e < deg) ? wrow[e] : 0.f;
            acc = fma4h(w, pU[t], acc);
        }
        // tail for deg > 32 (rare)
        int j = 32;
        for (; j + 4 <= deg; j += 4) {
            int s = sldsHC[j + sub];
            float w = wrow[j + sub];
            uint2 u = *reinterpret_cast<const uint2*>(&h[s + hoff]);
            acc = fma4h(w, u, acc);
        }
        if (j < deg && sub < deg - j) {
            int s = sldsHC[j + sub];
            float w = wrow[j + sub];
            uint2 u = *reinterpret_cast<const uint2*>(&h[s + hoff]);
            acc = fma4h(w, u, acc);
        }
#pragma unroll
        for (int off = 16; off <= 32; off <<= 1) {
            acc.x += __shfl_xor(acc.x, off);
            acc.y += __shfl_xor(acc.y, off);
            acc.z += __shfl_xor(acc.z, off);
            acc.w += __shfl_xor(acc.w, off);
        }
        if (lane < 16) {
            float inv = 1.f / (ssum + 1e-16f);
            const float4 b4 = *reinterpret_cast<const float4*>(&bias[head * CDIM + l16 * 4]);
            float4 o;
            o.x = fmaxf(fmaf(acc.x, inv, b4.x), 0.f);
            o.y = fmaxf(fmaf(acc.y, inv, b4.y), 0.f);
            o.z = fmaxf(fmaf(acc.z, inv, b4.z), 0.f);
            o.w = fmaxf(fmaf(acc.w, inv, b4.w), 0.f);
            *reinterpret_cast<float4*>(&out[(size_t)n * HC + head * CDIM + l16 * 4]) = o;
        }
    } else {  // streaming fallback (not hit for this graph; correctness-safe)
        float m = -1e30f;
        for (int j = start + lane; j < start + deg; j += 64) {
            float a = al_src[csr_src[j] * 3 + head] + ad;
            a = a > 0.f ? a : 0.2f * a;
            m = fmaxf(m, a);
        }
#pragma unroll
        for (int off = 32; off; off >>= 1) m = fmaxf(m, __shfl_xor(m, off));
        float acc = 0.f, ssum = 0.f;
        for (int j = start; j < start + deg; ++j) {
            int s = csr_src[j];
            float a = al_src[s * 3 + head] + ad;
            a = a > 0.f ? a : 0.2f * a;
            float w = __expf(a - m);
            ssum += w;
            acc = fmaf(w, __half2float(h[(size_t)s * HC + head * CDIM + lane]), acc);
        }
        float o = acc / (ssum + 1e-16f) + bias[head * CDIM + lane];
        out[(size_t)n * HC + head * CDIM + lane] = fmaxf(o, 0.f);
    }
}

// ---------------------------------------------------------------------------
// mu/lv aggregation fused over interleaved hml[n][384]: 3 waves/node.
// Same T14 async-split: 16 gather loads ([0,32) x mu/lv) issued before the
// softmax phase; weights computed from registers; LDS holds exp weights only.
// ---------------------------------------------------------------------------
__global__ __launch_bounds__(192) void agg_mean2_kernel(const int* __restrict__ row_ptr,
                                                        const int* __restrict__ csr_src,
                                                        const __half* __restrict__ hml,
                                                        const float* __restrict__ alms,
                                                        const float* __restrict__ almd,
                                                        const float* __restrict__ alls,
                                                        const float* __restrict__ alld,
                                                        const float* __restrict__ b_mu,
                                                        const float* __restrict__ b_lv,
                                                        float* __restrict__ out) {
    __shared__ int slds3[MAXDEG];
    __shared__ int sldsML[MAXDEG];
    __shared__ float wm_[3][MAXDEG], wl_[3][MAXDEG];
    __shared__ __align__(16) float red[6][64];
    int n = blockIdx.x;
    int head = threadIdx.x >> 6;   // 0..2
    int lane = threadIdx.x & 63;
    int start = row_ptr[n];
    int deg = row_ptr[n + 1] - start;
    float adm = almd[n * 3 + head];
    float adl = alld[n * 3 + head];

    if (deg <= MAXDEG) {
        if (threadIdx.x < deg) {
            int s = csr_src[start + threadIdx.x];
            slds3[threadIdx.x] = s * 3;
            sldsML[threadIdx.x] = s * MLW;
        }
        __syncthreads();
        const int sub = lane >> 4, l16 = lane & 15;
        const int hoffm = head * CDIM + l16 * 4;
        const int hoffl = hoffm + 192;

        // phase 1: attention-logit loads (oldest in vmcnt queue)
        float amr0 = -1e30f, avr0 = -1e30f, amr1 = -1e30f, avr1 = -1e30f;
        if (lane < deg) {
            int idx = slds3[lane] + head;
            amr0 = alms[idx] + adm;
            avr0 = alls[idx] + adl;
        }
        if (lane + 64 < deg) {
            int idx = slds3[lane + 64] + head;
            amr1 = alms[idx] + adm;
            avr1 = alls[idx] + adl;
        }

        // phase 2: issue gather preloads for edges [0,32), mu+lv halves
        uint2 pM[8], pL[8];
#pragma unroll
        for (int t = 0; t < 8; ++t) {
            int e = (t >> 2) * 16 + (t & 3) * 4 + sub;
            pM[t] = make_uint2(0u, 0u);
            pL[t] = make_uint2(0u, 0u);
            if (e < deg) {
                int s = sldsML[e];
                pM[t] = *reinterpret_cast<const uint2*>(&hml[s + hoffm]);
                pL[t] = *reinterpret_cast<const uint2*>(&hml[s + hoffl]);
            }
        }
        __builtin_amdgcn_sched_barrier(0);   // pin load issue above softmax

        // phase 3: softmax for mu and lv (register inputs, loads in flight)
        float am0 = amr0 > 0.f ? amr0 : 0.2f * amr0;
        float av0 = avr0 > 0.f ? avr0 : 0.2f * avr0;
        float am1 = amr1 > 0.f ? amr1 : 0.2f * amr1;
        float av1 = avr1 > 0.f ? avr1 : 0.2f * avr1;
        float mm = fmaxf(am0, am1), ml = fmaxf(av0, av1);
#pragma unroll
        for (int off = 32; off; off >>= 1) {
            mm = fmaxf(mm, __shfl_xor(mm, off));
            ml = fmaxf(ml, __shfl_xor(ml, off));
        }
        float sm = 0.f, sl = 0.f;
        if (lane < deg) {
            float em = __expf(am0 - mm); wm_[head][lane] = em; sm += em;
            float el = __expf(av0 - ml); wl_[head][lane] = el; sl += el;
        }
        if (lane + 64 < deg) {
            float em = __expf(am1 - mm); wm_[head][lane + 64] = em; sm += em;
            float el = __expf(av1 - ml); wl_[head][lane + 64] = el; sl += el;
        }
#pragma unroll
        for (int off = 32; off; off >>= 1) {
            sm += __shfl_xor(sm, off);
            sl += __shfl_xor(sl, off);
        }

        // phase 4: fma with preloaded values (same edge order as before)
        float4 am4 = make_float4(0.f, 0.f, 0.f, 0.f);
        float4 al4 = make_float4(0.f, 0.f, 0.f, 0.f);
#pragma unroll
        for (int t = 0; t < 8; ++t) {
            int e = (t >> 2) * 16 + (t & 3) * 4 + sub;
            float wmA = 0.f, wlA = 0.f;
            if (e < deg) { wmA = wm_[head][e]; wlA = wl_[head][e]; }
            am4 = fma4h(wmA, pM[t], am4);
            al4 = fma4h(wlA, pL[t], al4);
        }
        // tail for deg > 32 (rare)
        int j = 32;
        for (; j + 4 <= deg; j += 4) {
            int s = sldsML[j + sub];
            float wmA = wm_[head][j + sub], wlA = wl_[head][j + sub];
            uint2 uM = *reinterpret_cast<const uint2*>(&hml[s + hoffm]);
            uint2 uL = *reinterpret_cast<const uint2*>(&hml[s + hoffl]);
            am4 = fma4h(wmA, uM, am4); al4 = fma4h(wlA, uL, al4);
        }
        if (j < deg && sub < deg - j) {
            int s = sldsML[j + sub];
            float wmA = wm_[head][j + sub], wlA = wl_[head][j + sub];
            uint2 uM = *reinterpret_cast<const uint2*>(&hml[s + hoffm]);
            uint2 uL = *reinterpret_cast<const uint2*>(&hml[s + hoffl]);
            am4 = fma4h(wmA, uM, am4); al4 = fma4h(wlA, uL, al4);
        }
#pragma unroll
        for (int off = 16; off <= 32; off <<= 1) {
            am4.x += __shfl_xor(am4.x, off); am4.y += __shfl_xor(am4.y, off);
            am4.z += __shfl_xor(am4.z, off); am4.w += __shfl_xor(am4.w, off);
            al4.x += __shfl_xor(al4.x, off); al4.y += __shfl_xor(al4.y, off);
            al4.z += __shfl_xor(al4.z, off); al4.w += __shfl_xor(al4.w, off);
        }
        if (lane < 16) {
            float invm = 1.f / (sm + 1e-16f);
            float invl = 1.f / (sl + 1e-16f);
            float4 rm, rl;
            rm.x = am4.x * invm; rm.y = am4.y * invm; rm.z = am4.z * invm; rm.w = am4.w * invm;
            rl.x = al4.x * invl; rl.y = al4.y * invl; rl.z = al4.z * invl; rl.w = al4.w * invl;
            *reinterpret_cast<float4*>(&red[head][l16 * 4]) = rm;
            *reinterpret_cast<float4*>(&red[3 + head][l16 * 4]) = rl;
        }
    } else {  // streaming fallback (not hit; correctness-safe)
        for (int pass = 0; pass < 2; ++pass) {
            const float* as = pass ? alls : alms;
            float ad = pass ? adl : adm;
            int coff = pass ? 192 : 0;
            float m = -1e30f;
            for (int j = start + lane; j < start + deg; j += 64) {
                float a = as[csr_src[j] * 3 + head] + ad;
                a = a > 0.f ? a : 0.2f * a;
                m = fmaxf(m, a);
            }
#pragma unroll
            for (int off = 32; off; off >>= 1) m = fmaxf(m, __shfl_xor(m, off));
            float acc = 0.f, ssum = 0.f;
            for (int j = start; j < start + deg; ++j) {
                int s = csr_src[j];
                float a = as[s * 3 + head] + ad;
                a = a > 0.f ? a : 0.2f * a;
                float w = __expf(a - m);
                ssum += w;
                acc = fmaf(w, __half2float(hml[(size_t)s * MLW + coff + head * CDIM + lane]), acc);
            }
            red[pass * 3 + head][lane] = acc / (ssum + 1e-16f);
        }
    }
    __syncthreads();
    if (threadIdx.x < 64) {
        out[(size_t)n * CDIM + lane] =
            (red[0][lane] + red[1][lane] + red[2][lane]) * (1.f / 3.f) + b_mu[lane];
    } else if (threadIdx.x < 128) {
        out[(size_t)NN * CDIM + (size_t)n * CDIM + lane] =
            (red[3][lane] + red[4][lane] + red[5][lane]) * (1.f / 3.f) + b_lv[lane];
    }
}

// ---------------------------------------------------------------------------
extern "C" void kernel_launch(void* const* d_in, const int* in_sizes, int n_in,
                              void* d_out, int out_size, void* d_ws, size_t ws_size,
                              hipStream_t stream) {
    const float* x    = (const float*)d_in[0];
    const int*   ei   = (const int*)d_in[1];
    const float* W1   = (const float*)d_in[2];
    const float* a1s  = (const float*)d_in[3];
    const float* a1d  = (const float*)d_in[4];
    const float* b1   = (const float*)d_in[5];
    const float* Wmu  = (const float*)d_in[6];
    const float* amus = (const float*)d_in[7];
    const float* amud = (const float*)d_in[8];
    const float* bmu  = (const float*)d_in[9];
    const float* Wlv  = (const float*)d_in[10];
    const float* alvs = (const float*)d_in[11];
    const float* alvd = (const float*)d_in[12];
    const float* blv  = (const float*)d_in[13];
    float* out = (float*)d_out;

    // workspace carve (256B aligned)
    size_t off = 0;
    auto carve = [&](size_t bytes) {
        void* p = (char*)d_ws + off;
        off += (bytes + 255) & ~(size_t)255;
        return p;
    };
    int*    cnt      = (int*)carve((size_t)NN * 4);
    int*    row_ptr  = (int*)carve((size_t)(NN + 1) * 4);
    int*    partials = (int*)carve(64 * 4);
    int*    csr      = (int*)carve((size_t)ET * 4);
    __half* h1f16    = (__half*)carve((size_t)NN * HC * 2);
    float*  hrelu    = (float*)carve((size_t)NN * HC * 4);
    __half* hml      = (__half*)carve((size_t)NN * MLW * 2);
    float*  al1s     = (float*)carve((size_t)NN * 3 * 4);
    float*  al1d     = (float*)carve((size_t)NN * 3 * 4);
    float*  alms     = (float*)carve((size_t)NN * 3 * 4);
    float*  almd     = (float*)carve((size_t)NN * 3 * 4);
    float*  alls     = (float*)carve((size_t)NN * 3 * 4);
    float*  alld     = (float*)carve((size_t)NN * 3 * 4);

    const int scan_blocks = (NN + SCAN_BLK - 1) / SCAN_BLK;  // 49

    // ---- CSR build (shared by all 3 layers) ----
    hipMemsetAsync(cnt, 0, (size_t)NN * 4, stream);
    hist_kernel<<<(ET + 255) / 256, 256, 0, stream>>>(ei, cnt);
    scan1_kernel<<<scan_blocks, SCAN_BLK, 0, stream>>>(cnt, row_ptr, partials);
    scan2_kernel<<<1, 64, 0, stream>>>(partials, scan_blocks);
    scan3_kernel<<<scan_blocks, SCAN_BLK, 0, stream>>>(row_ptr, partials, cnt);
    scatter_kernel<<<(ET + 255) / 256, 256, 0, stream>>>(ei, cnt, row_ptr, csr);

    // ---- Layer 1 (fp16 h) ----
    dim3 g1((NN + 127) / 128, HC / 64);
    sgemm1<<<g1, 256, 0, stream>>>(x, W1, h1f16);
    al_h_kernel<<<(NN * 3 + 3) / 4, 256, 0, stream>>>(h1f16, a1s, a1d, al1s, al1d);
    agg_cat_kernel<<<NN, 192, 0, stream>>>(row_ptr, csr, h1f16, al1s, al1d, b1, hrelu);

    // ---- Layers mu / lv fused: one GEMM (N=384), one al pass ----
    dim3 g2((NN + 127) / 128, MLW / 64);
    sgemm23<<<g2, 256, 0, stream>>>(hrelu, Wmu, Wlv, hml);
    al_ml_kernel<<<(NN * 3 + 3) / 4, 256, 0, stream>>>(hml, amus, amud, alvs, alvd,
                                                       alms, almd, alls, alld);
    agg_mean2_kernel<<<NN, 192, 0, stream>>>(row_ptr, csr, hml,
                                             alms, almd, alls, alld, bmu, blv, out);
}